// Round 5
// baseline (603.715 us; speedup 1.0000x reference)
//
#include <hip/hip_runtime.h>
#include <hip/hip_bf16.h>
#include <math.h>

// ---------------------------------------------------------------------------
// DDiTBlockCausal: B=2, S=2048, D=1024, H=16, Dh=64, MLP=4096, fp32 I/O.
// Round 4: R3 design with the LDS overflow fixed (PPAD 40 -> 72; 64-key rows
// no longer spill into the neighboring wave's P slab).
// ---------------------------------------------------------------------------

#define B_ 2
#define S_ 2048
#define D_ 1024
#define H_ 16
#define DH_ 64
#define MLP_ 4096
#define ROWS_ (B_ * S_)   // 4096

typedef short bf16x8 __attribute__((ext_vector_type(8)));
typedef float f32x4 __attribute__((ext_vector_type(4)));
typedef unsigned short ushort_t;
typedef ushort_t u16x4 __attribute__((ext_vector_type(4)));
typedef unsigned int u32x2 __attribute__((ext_vector_type(2)));

__device__ __forceinline__ float wave_reduce_sum(float v) {
  #pragma unroll
  for (int off = 32; off > 0; off >>= 1) v += __shfl_down(v, off, 64);
  return v;
}

__device__ __forceinline__ ushort_t f2bf(float v) {
  __hip_bfloat16 h = __float2bfloat16(v);
  return *(ushort_t*)&h;
}
__device__ __forceinline__ float bf2f(ushort_t u) {
  unsigned int v = ((unsigned int)u) << 16;
  union { unsigned int i; float f; } c; c.i = v; return c.f;
}

__device__ __forceinline__ void async_copy16(const void* g, void* l) {
  __builtin_amdgcn_global_load_lds(
      (const __attribute__((address_space(1))) void*)g,
      (__attribute__((address_space(3))) void*)l, 16, 0, 0);
}

// ---------------- weight cast fp32 -> bf16 (4 tensors, blockIdx.y picks) ---
__global__ __launch_bounds__(256) void cast_w_kernel(
    const float* __restrict__ s0, ushort_t* __restrict__ d0, int n0,
    const float* __restrict__ s1, ushort_t* __restrict__ d1, int n1,
    const float* __restrict__ s2, ushort_t* __restrict__ d2, int n2,
    const float* __restrict__ s3, ushort_t* __restrict__ d3, int n3) {
  const float* s; ushort_t* d; int n;
  switch (blockIdx.y) {
    case 0: s = s0; d = d0; n = n0; break;
    case 1: s = s1; d = d1; n = n1; break;
    case 2: s = s2; d = d2; n = n2; break;
    default: s = s3; d = d3; n = n3; break;
  }
  const int i = (blockIdx.x * 256 + threadIdx.x) * 4;
  if (i < n) {
    const float4 v = *reinterpret_cast<const float4*>(s + i);
    u16x4 o;
    o[0] = f2bf(v.x); o[1] = f2bf(v.y); o[2] = f2bf(v.z); o[3] = f2bf(v.w);
    *reinterpret_cast<u16x4*>(d + i) = o;
  }
}

// ---------------- LayerNorm: fp32 in, bf16 out -----------------------------
__global__ __launch_bounds__(256) void ln_kernel(
    const float* __restrict__ x, const float* __restrict__ w,
    ushort_t* __restrict__ y) {
  const int row = blockIdx.x;
  const float4 v = reinterpret_cast<const float4*>(x + (size_t)row * D_)[threadIdx.x];
  float s  = v.x + v.y + v.z + v.w;
  float ss = v.x * v.x + v.y * v.y + v.z * v.z + v.w * v.w;
  __shared__ float red[8];
  const int wave = threadIdx.x >> 6, lane = threadIdx.x & 63;
  const float ws1 = wave_reduce_sum(s);
  const float ws2 = wave_reduce_sum(ss);
  if (lane == 0) { red[wave] = ws1; red[4 + wave] = ws2; }
  __syncthreads();
  const float tot  = red[0] + red[1] + red[2] + red[3];
  const float tot2 = red[4] + red[5] + red[6] + red[7];
  const float mu  = tot * (1.0f / D_);
  const float var = tot2 * (1.0f / D_) - mu * mu;
  const float inv = rsqrtf(var + 1e-5f);
  const float4 wv = reinterpret_cast<const float4*>(w)[threadIdx.x];
  u16x4 o;
  o[0] = f2bf((v.x - mu) * inv * wv.x);
  o[1] = f2bf((v.y - mu) * inv * wv.y);
  o[2] = f2bf((v.z - mu) * inv * wv.z);
  o[3] = f2bf((v.w - mu) * inv * wv.w);
  reinterpret_cast<u16x4*>(y + (size_t)row * D_)[threadIdx.x] = o;
}

// ---------------- bf16 MFMA GEMM: C[M,N] = A[M,K] * W[N,K]^T ---------------
// m97 structure. FUSE bits: 1=+bias, 2=gelu, 4=+res (fp32).
// QKV=1: cols n>=2048 (the V part) are stored transposed-bf16 into Vt
// (B,H,Dh,S) instead of C — V needs no RoPE, and attention wants V^T.
__device__ __forceinline__ float gelu_tanh(float u) {
  const float u3 = u * u * u;
  const float t = tanhf(0.7978845608028654f * (u + 0.044715f * u3));
  return 0.5f * u * (1.0f + t);
}

template <int FUSE, int OUTBF, int QKV>
__global__ __launch_bounds__(256) void gemm_bt(
    const ushort_t* __restrict__ A, const ushort_t* __restrict__ W,
    const float* __restrict__ bias, const float* __restrict__ res,
    void* __restrict__ Cv, ushort_t* __restrict__ VtOut,
    int M, int N, int K) {
  __shared__ ushort_t As[128 * 32];
  __shared__ ushort_t Bs[128 * 32];
  const int tid = threadIdx.x;
  const int wave = tid >> 6, lane = tid & 63;
  const int l15 = lane & 15, quad = lane >> 4;
  const int m0 = blockIdx.y * 128, n0 = blockIdx.x * 128;
  const int wm = (wave & 1) * 64, wn = (wave >> 1) * 64;

  const int srow = tid >> 2;           // 0..63
  const int scol = (tid & 3) * 8;      // 0,8,16,24 (elements)
  const ushort_t* Ag = A + (size_t)(m0 + srow) * K + scol;
  const ushort_t* Wg = W + (size_t)(n0 + srow) * K + scol;

  f32x4 acc[4][4] = {};

  for (int k0 = 0; k0 < K; k0 += 32) {
    __syncthreads();
    async_copy16(Ag + k0,            &As[srow * 32 + scol]);
    async_copy16(Ag + 64 * K + k0,   &As[(64 + srow) * 32 + scol]);
    async_copy16(Wg + k0,            &Bs[srow * 32 + scol]);
    async_copy16(Wg + 64 * K + k0,   &Bs[(64 + srow) * 32 + scol]);
    __syncthreads();

    bf16x8 af[4], bfr[4];
    #pragma unroll
    for (int i = 0; i < 4; ++i) {
      af[i]  = *(const bf16x8*)&As[(wm + i * 16 + l15) * 32 + quad * 8];
      bfr[i] = *(const bf16x8*)&Bs[(wn + i * 16 + l15) * 32 + quad * 8];
    }
    #pragma unroll
    for (int i = 0; i < 4; ++i)
      #pragma unroll
      for (int j = 0; j < 4; ++j)
        acc[i][j] = __builtin_amdgcn_mfma_f32_16x16x32_bf16(af[i], bfr[j], acc[i][j], 0, 0, 0);
  }

  #pragma unroll
  for (int i = 0; i < 4; ++i) {
    const int mb = m0 + wm + i * 16 + quad * 4;     // + r
    #pragma unroll
    for (int j = 0; j < 4; ++j) {
      const int n = n0 + wn + j * 16 + l15;
      float cv[4];
      #pragma unroll
      for (int r = 0; r < 4; ++r) {
        float c = acc[i][j][r];
        if (FUSE & 1) c += bias[n];
        if (FUSE & 2) c = gelu_tanh(c);
        if (FUSE & 4) c += res[(size_t)(mb + r) * N + n];
        cv[r] = c;
      }
      if (QKV && ((n0 + wn) >> 10) == 2) {
        // V part: transposed bf16 store to Vt (B,H,Dh,S)
        const int d  = n & 63;
        const int hh = (n >> 6) & 15;
        const int bb = mb >> 11;
        const int ss = mb & (S_ - 1);
        u16x4 pk;
        #pragma unroll
        for (int r = 0; r < 4; ++r) pk[r] = f2bf(cv[r]);
        *(u16x4*)&VtOut[((size_t)(bb * H_ + hh) * DH_ + d) * S_ + ss] = pk;
      } else {
        #pragma unroll
        for (int r = 0; r < 4; ++r) {
          if (OUTBF) ((ushort_t*)Cv)[(size_t)(mb + r) * N + n] = f2bf(cv[r]);
          else       ((float*)Cv)[(size_t)(mb + r) * N + n]   = cv[r];
        }
      }
    }
  }
}

// ---------------- RoPE (q,k only) + transpose to (B,H,S,Dh), bf16 ---------
// Q pre-scaled by 1/sqrt(Dh) = 0.125 (exact in bf16).
__global__ __launch_bounds__(256) void rope_kernel(
    const ushort_t* __restrict__ qkv, const float* __restrict__ cosb,
    const float* __restrict__ sinb, ushort_t* __restrict__ Qo,
    ushort_t* __restrict__ Ko) {
  const int bs = blockIdx.x;           // b*S + s
  const int s  = bs & (S_ - 1);
  const int b  = bs >> 11;
  const int t  = threadIdx.x;
  const ushort_t* base = qkv + (size_t)bs * (3 * D_);
  #pragma unroll
  for (int i = 0; i < 8; ++i) {        // q,k only: e in [0, 2048)
    const int e = i * 256 + t;
    const int which = e >> 10;         // 0=q, 1=k
    const int rem = e & 1023;
    const int h = rem >> 6;
    const int d = rem & 63;
    const float val = bf2f(base[e]);
    float out;
    if (d < 32) {
      out = val * cosb[s * 64 + d] - bf2f(base[e + 32]) * sinb[s * 64 + d];
    } else {
      out = val * cosb[s * 64 + d - 32] + bf2f(base[e - 32]) * sinb[s * 64 + d - 32];
    }
    const size_t oidx = (((size_t)(b * H_ + h)) * S_ + s) * DH_ + d;
    if (which == 0) Qo[oidx] = f2bf(out * 0.125f);
    else            Ko[oidx] = f2bf(out);
  }
}

// ---------------- Barrier-free transposed flash attention ------------------
// Q,K bf16 (B,H,S,Dh); Vt bf16 (B,H,Dh,S); O bf16 (B,S,H,Dh).
// One wave = 16 queries, fully independent (no __syncthreads).
// S^T = K Q^T  -> C layout: col(lane&15)=query, row=key  => per-lane (m,l).
// O^T = V^T P^T -> C layout: col=query, row=dh.
// PPAD=72: 64-key rows + 8 pad; row = 144 B (16B-aligned, 2-way banks = free).
#define PPAD 72

__global__ __launch_bounds__(256) void attn_kernel(
    const ushort_t* __restrict__ Qb, const ushort_t* __restrict__ Kb,
    const ushort_t* __restrict__ Vt, ushort_t* __restrict__ O) {
  const int wave = threadIdx.x >> 6;
  const int lane = threadIdx.x & 63;
  const int l15 = lane & 15, quad = lane >> 4;
  const int bh = blockIdx.y;
  const int b = bh >> 4, h = bh & 15;
  const int qw = (gridDim.x * 4 - 1) - (blockIdx.x * 4 + wave);  // big first
  const int q0 = qw * 16;

  __shared__ ushort_t Plds[4][16 * PPAD];
  ushort_t* Pw = &Plds[wave][0];

  const ushort_t* Kbh = Kb + (size_t)bh * S_ * DH_;
  const ushort_t* Vbh = Vt + (size_t)bh * DH_ * S_;

  // Q B-fragment: B[n=query(l15)][k=dh(quad*8+j)]
  const ushort_t* qptr = Qb + ((size_t)bh * S_ + q0 + l15) * DH_ + quad * 8;
  const bf16x8 qb0 = *(const bf16x8*)(qptr);
  const bf16x8 qb1 = *(const bf16x8*)(qptr + 32);

  f32x4 o_acc[4] = {};                 // O^T[dh = mt*16+quad*4+r][q = l15]
  float m_run = -1e30f, l_run = 0.0f;  // per query (l15)

  const int nfull = q0 >> 6;
  for (int c = 0; c <= nfull; ++c) {
    const int k0 = c << 6;

    // S^T tiles: st[kt] holds S^T[key = k0+kt*16+quad*4+r][q = l15]
    f32x4 st[4];
    #pragma unroll
    for (int kt = 0; kt < 4; ++kt) {
      const ushort_t* kp = Kbh + (size_t)(k0 + kt * 16 + l15) * DH_ + quad * 8;
      const bf16x8 ka0 = *(const bf16x8*)kp;
      const bf16x8 ka1 = *(const bf16x8*)(kp + 32);
      f32x4 z = {0.0f, 0.0f, 0.0f, 0.0f};
      z = __builtin_amdgcn_mfma_f32_16x16x32_bf16(ka0, qb0, z, 0, 0, 0);
      z = __builtin_amdgcn_mfma_f32_16x16x32_bf16(ka1, qb1, z, 0, 0, 0);
      st[kt] = z;
    }

    // V^T A-fragments: A[m=dh(l15)][k=key(quad*8+j)] — contiguous global 16B
    bf16x8 va[4][2];
    #pragma unroll
    for (int mt = 0; mt < 4; ++mt) {
      const ushort_t* vp = Vbh + (size_t)(mt * 16 + l15) * S_ + k0 + quad * 8;
      va[mt][0] = *(const bf16x8*)vp;
      va[mt][1] = *(const bf16x8*)(vp + 32);
    }

    // causal mask (only the chunk containing the diagonal)
    if (c == nfull) {
      #pragma unroll
      for (int kt = 0; kt < 4; ++kt)
        #pragma unroll
        for (int r = 0; r < 4; ++r)
          if (k0 + kt * 16 + quad * 4 + r > q0 + l15) st[kt][r] = -1e30f;
    }

    // online softmax, per-query scalar stats (2 shuffles per reduction)
    float mx = -1e30f;
    #pragma unroll
    for (int kt = 0; kt < 4; ++kt)
      #pragma unroll
      for (int r = 0; r < 4; ++r) mx = fmaxf(mx, st[kt][r]);
    mx = fmaxf(mx, __shfl_xor(mx, 16, 64));
    mx = fmaxf(mx, __shfl_xor(mx, 32, 64));
    const float m_new = fmaxf(m_run, mx);
    const float alpha = __expf(m_run - m_new);
    float p[4][4];
    float rs = 0.0f;
    #pragma unroll
    for (int kt = 0; kt < 4; ++kt)
      #pragma unroll
      for (int r = 0; r < 4; ++r) {
        const float e = __expf(st[kt][r] - m_new);
        p[kt][r] = e;
        rs += e;
      }
    rs += __shfl_xor(rs, 16, 64);
    rs += __shfl_xor(rs, 32, 64);
    l_run = l_run * alpha + rs;
    m_run = m_new;
    #pragma unroll
    for (int mt = 0; mt < 4; ++mt)
      #pragma unroll
      for (int r = 0; r < 4; ++r) o_acc[mt][r] *= alpha;

    // P^T: C-layout -> per-wave LDS -> B-fragment (row=query, col=key)
    #pragma unroll
    for (int kt = 0; kt < 4; ++kt) {
      u32x2 wpair;
      wpair[0] = (unsigned)f2bf(p[kt][0]) | ((unsigned)f2bf(p[kt][1]) << 16);
      wpair[1] = (unsigned)f2bf(p[kt][2]) | ((unsigned)f2bf(p[kt][3]) << 16);
      *(u32x2*)&Pw[l15 * PPAD + kt * 16 + quad * 4] = wpair;
    }
    asm volatile("s_waitcnt lgkmcnt(0)" ::: "memory");
    const bf16x8 pb0 = *(const bf16x8*)&Pw[l15 * PPAD + quad * 8];
    const bf16x8 pb1 = *(const bf16x8*)&Pw[l15 * PPAD + 32 + quad * 8];

    // O^T += V^T P^T
    #pragma unroll
    for (int mt = 0; mt < 4; ++mt) {
      o_acc[mt] = __builtin_amdgcn_mfma_f32_16x16x32_bf16(va[mt][0], pb0, o_acc[mt], 0, 0, 0);
      o_acc[mt] = __builtin_amdgcn_mfma_f32_16x16x32_bf16(va[mt][1], pb1, o_acc[mt], 0, 0, 0);
    }
  }

  // epilogue: normalize, store bf16 to (B,S,H,Dh); r-consecutive dh -> 8B packs
  const float inv = 1.0f / l_run;
  #pragma unroll
  for (int mt = 0; mt < 4; ++mt) {
    u16x4 pk;
    #pragma unroll
    for (int r = 0; r < 4; ++r) pk[r] = f2bf(o_acc[mt][r] * inv);
    *(u16x4*)&O[(((size_t)b * S_ + q0 + l15) * H_ + h) * DH_ + mt * 16 + quad * 4] = pk;
  }
}

// ---------------------------------------------------------------------------
extern "C" void kernel_launch(void* const* d_in, const int* in_sizes, int n_in,
                              void* d_out, int out_size, void* d_ws, size_t ws_size,
                              hipStream_t stream) {
  const float* x       = (const float*)d_in[0];
  const float* rot_cos = (const float*)d_in[1];
  const float* rot_sin = (const float*)d_in[2];
  const float* ln1_w   = (const float*)d_in[3];
  const float* w_qkv   = (const float*)d_in[4];
  const float* w_out   = (const float*)d_in[5];
  const float* ln2_w   = (const float*)d_in[6];
  const float* w_mlp1  = (const float*)d_in[7];
  const float* b_mlp1  = (const float*)d_in[8];
  const float* w_mlp2  = (const float*)d_in[9];
  const float* b_mlp2  = (const float*)d_in[10];
  float* out = (float*)d_out;

  char* wsb = (char*)d_ws;
  const size_t MB = 1u << 20;
  ushort_t* h1_bf  = (ushort_t*)(wsb + 0 * MB);    // 8 MB  (reused as h2)
  ushort_t* qkv_bf = (ushort_t*)(wsb + 8 * MB);    // 24 MB (V third unused)
  ushort_t* q_bf   = (ushort_t*)(wsb + 32 * MB);   // 8 MB
  ushort_t* k_bf   = (ushort_t*)(wsb + 40 * MB);   // 8 MB
  ushort_t* v_t    = (ushort_t*)(wsb + 48 * MB);   // 8 MB (B,H,Dh,S)
  ushort_t* o_bf   = (ushort_t*)(wsb + 56 * MB);   // 8 MB
  float*    x2     = (float*)   (wsb + 64 * MB);   // 16 MB
  ushort_t* u_bf   = (ushort_t*)(wsb + 80 * MB);   // 32 MB
  ushort_t* wq_bf  = (ushort_t*)(wsb + 112 * MB);  // 6 MB
  ushort_t* wo_bf  = (ushort_t*)(wsb + 118 * MB);  // 2 MB
  ushort_t* w1_bf  = (ushort_t*)(wsb + 120 * MB);  // 8 MB
  ushort_t* w2_bf  = (ushort_t*)(wsb + 128 * MB);  // 8 MB -> 136 MB total
  (void)ws_size; (void)in_sizes; (void)n_in; (void)out_size;

  dim3 b256(256);

  // 0) weights -> bf16
  cast_w_kernel<<<dim3(4096, 4), b256, 0, stream>>>(
      w_qkv, wq_bf, 3 * D_ * D_, w_out, wo_bf, D_ * D_,
      w_mlp1, w1_bf, MLP_ * D_, w_mlp2, w2_bf, MLP_ * D_);
  // 1) h1 = LN(x) * ln1_w -> bf16
  ln_kernel<<<dim3(ROWS_), b256, 0, stream>>>(x, ln1_w, h1_bf);
  // 2) qkv = h1 @ w_qkv^T; q,k -> qkv_bf, V -> v_t transposed (B,H,Dh,S)
  gemm_bt<0, 1, 1><<<dim3(3 * D_ / 128, ROWS_ / 128), b256, 0, stream>>>(
      h1_bf, wq_bf, nullptr, nullptr, qkv_bf, v_t, ROWS_, 3 * D_, D_);
  // 3) rope q,k -> (B,H,S,Dh) bf16
  rope_kernel<<<dim3(ROWS_), b256, 0, stream>>>(qkv_bf, rot_cos, rot_sin, q_bf, k_bf);
  // 4) flash attention -> o (B,S,H,Dh) bf16
  attn_kernel<<<dim3(S_ / 64, B_ * H_), b256, 0, stream>>>(q_bf, k_bf, v_t, o_bf);
  // 5) x2 = x + o @ w_out^T -> fp32
  gemm_bt<4, 0, 0><<<dim3(D_ / 128, ROWS_ / 128), b256, 0, stream>>>(
      o_bf, wo_bf, nullptr, x, x2, nullptr, ROWS_, D_, D_);
  // 6) h2 = LN(x2) * ln2_w -> bf16
  ln_kernel<<<dim3(ROWS_), b256, 0, stream>>>(x2, ln2_w, h1_bf);
  // 7) u = gelu(h2 @ w_mlp1^T + b1) -> bf16
  gemm_bt<3, 1, 0><<<dim3(MLP_ / 128, ROWS_ / 128), b256, 0, stream>>>(
      h1_bf, w1_bf, b_mlp1, nullptr, u_bf, nullptr, ROWS_, MLP_, D_);
  // 8) out = x2 + u @ w_mlp2^T + b2 -> fp32
  gemm_bt<5, 0, 0><<<dim3(D_ / 128, ROWS_ / 128), b256, 0, stream>>>(
      u_bf, w2_bf, b_mlp2, x2, out, nullptr, ROWS_, D_, MLP_);
}

// Round 6
// 443.364 us; speedup vs baseline: 1.3617x; 1.3617x over previous
//
#include <hip/hip_runtime.h>
#include <hip/hip_bf16.h>
#include <math.h>

// ---------------------------------------------------------------------------
// DDiTBlockCausal: B=2, S=2048, D=1024, H=16, Dh=64, MLP=4096, fp32 I/O.
// Round 5: attention reworked for latency: 32 queries/wave (2x MFMA per K/V
// load), software-pipelined K prefetch, mirrored q-group load balancing.
// GEMMs / LN / rope unchanged from the passing R4 build.
// ---------------------------------------------------------------------------

#define B_ 2
#define S_ 2048
#define D_ 1024
#define H_ 16
#define DH_ 64
#define MLP_ 4096
#define ROWS_ (B_ * S_)   // 4096

typedef short bf16x8 __attribute__((ext_vector_type(8)));
typedef float f32x4 __attribute__((ext_vector_type(4)));
typedef unsigned short ushort_t;
typedef ushort_t u16x4 __attribute__((ext_vector_type(4)));
typedef unsigned int u32x2 __attribute__((ext_vector_type(2)));

__device__ __forceinline__ float wave_reduce_sum(float v) {
  #pragma unroll
  for (int off = 32; off > 0; off >>= 1) v += __shfl_down(v, off, 64);
  return v;
}

__device__ __forceinline__ ushort_t f2bf(float v) {
  __hip_bfloat16 h = __float2bfloat16(v);
  return *(ushort_t*)&h;
}
__device__ __forceinline__ float bf2f(ushort_t u) {
  unsigned int v = ((unsigned int)u) << 16;
  union { unsigned int i; float f; } c; c.i = v; return c.f;
}

__device__ __forceinline__ void async_copy16(const void* g, void* l) {
  __builtin_amdgcn_global_load_lds(
      (const __attribute__((address_space(1))) void*)g,
      (__attribute__((address_space(3))) void*)l, 16, 0, 0);
}

// ---------------- weight cast fp32 -> bf16 (4 tensors, blockIdx.y picks) ---
__global__ __launch_bounds__(256) void cast_w_kernel(
    const float* __restrict__ s0, ushort_t* __restrict__ d0, int n0,
    const float* __restrict__ s1, ushort_t* __restrict__ d1, int n1,
    const float* __restrict__ s2, ushort_t* __restrict__ d2, int n2,
    const float* __restrict__ s3, ushort_t* __restrict__ d3, int n3) {
  const float* s; ushort_t* d; int n;
  switch (blockIdx.y) {
    case 0: s = s0; d = d0; n = n0; break;
    case 1: s = s1; d = d1; n = n1; break;
    case 2: s = s2; d = d2; n = n2; break;
    default: s = s3; d = d3; n = n3; break;
  }
  const int i = (blockIdx.x * 256 + threadIdx.x) * 4;
  if (i < n) {
    const float4 v = *reinterpret_cast<const float4*>(s + i);
    u16x4 o;
    o[0] = f2bf(v.x); o[1] = f2bf(v.y); o[2] = f2bf(v.z); o[3] = f2bf(v.w);
    *reinterpret_cast<u16x4*>(d + i) = o;
  }
}

// ---------------- LayerNorm: fp32 in, bf16 out -----------------------------
__global__ __launch_bounds__(256) void ln_kernel(
    const float* __restrict__ x, const float* __restrict__ w,
    ushort_t* __restrict__ y) {
  const int row = blockIdx.x;
  const float4 v = reinterpret_cast<const float4*>(x + (size_t)row * D_)[threadIdx.x];
  float s  = v.x + v.y + v.z + v.w;
  float ss = v.x * v.x + v.y * v.y + v.z * v.z + v.w * v.w;
  __shared__ float red[8];
  const int wave = threadIdx.x >> 6, lane = threadIdx.x & 63;
  const float ws1 = wave_reduce_sum(s);
  const float ws2 = wave_reduce_sum(ss);
  if (lane == 0) { red[wave] = ws1; red[4 + wave] = ws2; }
  __syncthreads();
  const float tot  = red[0] + red[1] + red[2] + red[3];
  const float tot2 = red[4] + red[5] + red[6] + red[7];
  const float mu  = tot * (1.0f / D_);
  const float var = tot2 * (1.0f / D_) - mu * mu;
  const float inv = rsqrtf(var + 1e-5f);
  const float4 wv = reinterpret_cast<const float4*>(w)[threadIdx.x];
  u16x4 o;
  o[0] = f2bf((v.x - mu) * inv * wv.x);
  o[1] = f2bf((v.y - mu) * inv * wv.y);
  o[2] = f2bf((v.z - mu) * inv * wv.z);
  o[3] = f2bf((v.w - mu) * inv * wv.w);
  reinterpret_cast<u16x4*>(y + (size_t)row * D_)[threadIdx.x] = o;
}

// ---------------- bf16 MFMA GEMM: C[M,N] = A[M,K] * W[N,K]^T ---------------
// m97 structure. FUSE bits: 1=+bias, 2=gelu, 4=+res (fp32).
// QKV=1: cols n>=2048 (the V part) are stored transposed-bf16 into Vt
// (B,H,Dh,S) instead of C — V needs no RoPE, and attention wants V^T.
__device__ __forceinline__ float gelu_tanh(float u) {
  const float u3 = u * u * u;
  const float t = tanhf(0.7978845608028654f * (u + 0.044715f * u3));
  return 0.5f * u * (1.0f + t);
}

template <int FUSE, int OUTBF, int QKV>
__global__ __launch_bounds__(256) void gemm_bt(
    const ushort_t* __restrict__ A, const ushort_t* __restrict__ W,
    const float* __restrict__ bias, const float* __restrict__ res,
    void* __restrict__ Cv, ushort_t* __restrict__ VtOut,
    int M, int N, int K) {
  __shared__ ushort_t As[128 * 32];
  __shared__ ushort_t Bs[128 * 32];
  const int tid = threadIdx.x;
  const int wave = tid >> 6, lane = tid & 63;
  const int l15 = lane & 15, quad = lane >> 4;
  const int m0 = blockIdx.y * 128, n0 = blockIdx.x * 128;
  const int wm = (wave & 1) * 64, wn = (wave >> 1) * 64;

  const int srow = tid >> 2;           // 0..63
  const int scol = (tid & 3) * 8;      // 0,8,16,24 (elements)
  const ushort_t* Ag = A + (size_t)(m0 + srow) * K + scol;
  const ushort_t* Wg = W + (size_t)(n0 + srow) * K + scol;

  f32x4 acc[4][4] = {};

  for (int k0 = 0; k0 < K; k0 += 32) {
    __syncthreads();
    async_copy16(Ag + k0,            &As[srow * 32 + scol]);
    async_copy16(Ag + 64 * K + k0,   &As[(64 + srow) * 32 + scol]);
    async_copy16(Wg + k0,            &Bs[srow * 32 + scol]);
    async_copy16(Wg + 64 * K + k0,   &Bs[(64 + srow) * 32 + scol]);
    __syncthreads();

    bf16x8 af[4], bfr[4];
    #pragma unroll
    for (int i = 0; i < 4; ++i) {
      af[i]  = *(const bf16x8*)&As[(wm + i * 16 + l15) * 32 + quad * 8];
      bfr[i] = *(const bf16x8*)&Bs[(wn + i * 16 + l15) * 32 + quad * 8];
    }
    #pragma unroll
    for (int i = 0; i < 4; ++i)
      #pragma unroll
      for (int j = 0; j < 4; ++j)
        acc[i][j] = __builtin_amdgcn_mfma_f32_16x16x32_bf16(af[i], bfr[j], acc[i][j], 0, 0, 0);
  }

  #pragma unroll
  for (int i = 0; i < 4; ++i) {
    const int mb = m0 + wm + i * 16 + quad * 4;     // + r
    #pragma unroll
    for (int j = 0; j < 4; ++j) {
      const int n = n0 + wn + j * 16 + l15;
      float cv[4];
      #pragma unroll
      for (int r = 0; r < 4; ++r) {
        float c = acc[i][j][r];
        if (FUSE & 1) c += bias[n];
        if (FUSE & 2) c = gelu_tanh(c);
        if (FUSE & 4) c += res[(size_t)(mb + r) * N + n];
        cv[r] = c;
      }
      if (QKV && ((n0 + wn) >> 10) == 2) {
        // V part: transposed bf16 store to Vt (B,H,Dh,S)
        const int d  = n & 63;
        const int hh = (n >> 6) & 15;
        const int bb = mb >> 11;
        const int ss = mb & (S_ - 1);
        u16x4 pk;
        #pragma unroll
        for (int r = 0; r < 4; ++r) pk[r] = f2bf(cv[r]);
        *(u16x4*)&VtOut[((size_t)(bb * H_ + hh) * DH_ + d) * S_ + ss] = pk;
      } else {
        #pragma unroll
        for (int r = 0; r < 4; ++r) {
          if (OUTBF) ((ushort_t*)Cv)[(size_t)(mb + r) * N + n] = f2bf(cv[r]);
          else       ((float*)Cv)[(size_t)(mb + r) * N + n]   = cv[r];
        }
      }
    }
  }
}

// ---------------- RoPE (q,k only) + transpose to (B,H,S,Dh), bf16 ---------
// Q pre-scaled by 1/sqrt(Dh) = 0.125 (exact in bf16).
__global__ __launch_bounds__(256) void rope_kernel(
    const ushort_t* __restrict__ qkv, const float* __restrict__ cosb,
    const float* __restrict__ sinb, ushort_t* __restrict__ Qo,
    ushort_t* __restrict__ Ko) {
  const int bs = blockIdx.x;           // b*S + s
  const int s  = bs & (S_ - 1);
  const int b  = bs >> 11;
  const int t  = threadIdx.x;
  const ushort_t* base = qkv + (size_t)bs * (3 * D_);
  #pragma unroll
  for (int i = 0; i < 8; ++i) {        // q,k only: e in [0, 2048)
    const int e = i * 256 + t;
    const int which = e >> 10;         // 0=q, 1=k
    const int rem = e & 1023;
    const int h = rem >> 6;
    const int d = rem & 63;
    const float val = bf2f(base[e]);
    float out;
    if (d < 32) {
      out = val * cosb[s * 64 + d] - bf2f(base[e + 32]) * sinb[s * 64 + d];
    } else {
      out = val * cosb[s * 64 + d - 32] + bf2f(base[e - 32]) * sinb[s * 64 + d - 32];
    }
    const size_t oidx = (((size_t)(b * H_ + h)) * S_ + s) * DH_ + d;
    if (which == 0) Qo[oidx] = f2bf(out * 0.125f);
    else            Ko[oidx] = f2bf(out);
  }
}

// ---------------- Wave-autonomous transposed flash attention ---------------
// Q,K bf16 (B,H,S,Dh); Vt bf16 (B,H,Dh,S); O bf16 (B,S,H,Dh).
// One wave = 32 queries (2 q-tiles sharing each K/V fragment), no barriers.
// Mirrored q-group mapping balances causal work across waves/blocks.
// Pipeline: V loads issue at top of chunk; next chunk's K issues mid-chunk.
#define PPAD 72

__global__ __launch_bounds__(256) void attn_kernel(
    const ushort_t* __restrict__ Qb, const ushort_t* __restrict__ Kb,
    const ushort_t* __restrict__ Vt, ushort_t* __restrict__ O) {
  const int wave = threadIdx.x >> 6;
  const int lane = threadIdx.x & 63;
  const int l15 = lane & 15, quad = lane >> 4;
  const int bh = blockIdx.y;
  const int b = bh >> 4, h = bh & 15;
  const int wl = blockIdx.x * 4 + wave;            // 0..63 per bh
  const int g  = (wl & 1) ? (63 - (wl >> 1)) : (wl >> 1);
  const int q0 = g * 32;

  __shared__ ushort_t Plds[4][2][16 * PPAD];

  const ushort_t* Kbh = Kb + (size_t)bh * S_ * DH_;
  const ushort_t* Vbh = Vt + (size_t)bh * DH_ * S_;

  // Q B-fragments for both 16-query tiles
  bf16x8 qb[2][2];
  #pragma unroll
  for (int t = 0; t < 2; ++t) {
    const ushort_t* qptr = Qb + ((size_t)bh * S_ + q0 + t * 16 + l15) * DH_ + quad * 8;
    qb[t][0] = *(const bf16x8*)(qptr);
    qb[t][1] = *(const bf16x8*)(qptr + 32);
  }

  f32x4 o_acc[2][4] = {};              // [tile][dh-mt]; O^T layout
  float m_run[2] = {-1e30f, -1e30f}, l_run[2] = {0.0f, 0.0f};

  const int nch = (q0 >> 6) + 1;       // 64-key chunks (covers q0+31)

  // preload K fragments for chunk 0
  bf16x8 ka[4][2];
  #pragma unroll
  for (int kt = 0; kt < 4; ++kt) {
    const ushort_t* kp = Kbh + (size_t)(kt * 16 + l15) * DH_ + quad * 8;
    ka[kt][0] = *(const bf16x8*)kp;
    ka[kt][1] = *(const bf16x8*)(kp + 32);
  }

  for (int c = 0; c < nch; ++c) {
    const int k0 = c << 6;

    // V^T A-fragments for this chunk — issue first (consumed at end of body)
    bf16x8 va[4][2];
    #pragma unroll
    for (int mt = 0; mt < 4; ++mt) {
      const ushort_t* vp = Vbh + (size_t)(mt * 16 + l15) * S_ + k0 + quad * 8;
      va[mt][0] = *(const bf16x8*)vp;
      va[mt][1] = *(const bf16x8*)(vp + 32);
    }

    // S^T = K Q^T for both tiles
    f32x4 st[2][4];
    #pragma unroll
    for (int t = 0; t < 2; ++t)
      #pragma unroll
      for (int kt = 0; kt < 4; ++kt) {
        f32x4 z = {0.0f, 0.0f, 0.0f, 0.0f};
        z = __builtin_amdgcn_mfma_f32_16x16x32_bf16(ka[kt][0], qb[t][0], z, 0, 0, 0);
        z = __builtin_amdgcn_mfma_f32_16x16x32_bf16(ka[kt][1], qb[t][1], z, 0, 0, 0);
        st[t][kt] = z;
      }

    // prefetch next chunk's K fragments (hidden under softmax + PV)
    if (c + 1 < nch) {
      const int k1 = (c + 1) << 6;
      bf16x8 kan[4][2];
      #pragma unroll
      for (int kt = 0; kt < 4; ++kt) {
        const ushort_t* kp = Kbh + (size_t)(k1 + kt * 16 + l15) * DH_ + quad * 8;
        kan[kt][0] = *(const bf16x8*)kp;
        kan[kt][1] = *(const bf16x8*)(kp + 32);
      }
      #pragma unroll
      for (int kt = 0; kt < 4; ++kt) { ka[kt][0] = kan[kt][0]; ka[kt][1] = kan[kt][1]; }
    }

    // causal mask in the diagonal chunk
    if (c == nch - 1) {
      #pragma unroll
      for (int t = 0; t < 2; ++t) {
        const int query = q0 + t * 16 + l15;
        #pragma unroll
        for (int kt = 0; kt < 4; ++kt)
          #pragma unroll
          for (int r = 0; r < 4; ++r)
            if (k0 + kt * 16 + quad * 4 + r > query) st[t][kt][r] = -1e30f;
      }
    }

    // online softmax per tile (per-lane stats, 2 shuffles per reduction)
    #pragma unroll
    for (int t = 0; t < 2; ++t) {
      float mx = -1e30f;
      #pragma unroll
      for (int kt = 0; kt < 4; ++kt)
        #pragma unroll
        for (int r = 0; r < 4; ++r) mx = fmaxf(mx, st[t][kt][r]);
      mx = fmaxf(mx, __shfl_xor(mx, 16, 64));
      mx = fmaxf(mx, __shfl_xor(mx, 32, 64));
      const float m_new = fmaxf(m_run[t], mx);
      const float alpha = __expf(m_run[t] - m_new);
      float rs = 0.0f;
      #pragma unroll
      for (int kt = 0; kt < 4; ++kt)
        #pragma unroll
        for (int r = 0; r < 4; ++r) {
          const float e = __expf(st[t][kt][r] - m_new);
          st[t][kt][r] = e;
          rs += e;
        }
      rs += __shfl_xor(rs, 16, 64);
      rs += __shfl_xor(rs, 32, 64);
      l_run[t] = l_run[t] * alpha + rs;
      m_run[t] = m_new;
      #pragma unroll
      for (int mt = 0; mt < 4; ++mt)
        #pragma unroll
        for (int r = 0; r < 4; ++r) o_acc[t][mt][r] *= alpha;
    }

    // P^T transform (C-layout -> LDS -> B-fragment) and PV per tile
    #pragma unroll
    for (int t = 0; t < 2; ++t) {
      ushort_t* Pw = &Plds[wave][t][0];
      #pragma unroll
      for (int kt = 0; kt < 4; ++kt) {
        u32x2 wpair;
        wpair[0] = (unsigned)f2bf(st[t][kt][0]) | ((unsigned)f2bf(st[t][kt][1]) << 16);
        wpair[1] = (unsigned)f2bf(st[t][kt][2]) | ((unsigned)f2bf(st[t][kt][3]) << 16);
        *(u32x2*)&Pw[l15 * PPAD + kt * 16 + quad * 4] = wpair;
      }
      asm volatile("s_waitcnt lgkmcnt(0)" ::: "memory");
      const bf16x8 pb0 = *(const bf16x8*)&Pw[l15 * PPAD + quad * 8];
      const bf16x8 pb1 = *(const bf16x8*)&Pw[l15 * PPAD + 32 + quad * 8];
      #pragma unroll
      for (int mt = 0; mt < 4; ++mt) {
        o_acc[t][mt] = __builtin_amdgcn_mfma_f32_16x16x32_bf16(va[mt][0], pb0, o_acc[t][mt], 0, 0, 0);
        o_acc[t][mt] = __builtin_amdgcn_mfma_f32_16x16x32_bf16(va[mt][1], pb1, o_acc[t][mt], 0, 0, 0);
      }
    }
  }

  // epilogue: normalize, store bf16 to (B,S,H,Dh)
  #pragma unroll
  for (int t = 0; t < 2; ++t) {
    const float inv = 1.0f / l_run[t];
    #pragma unroll
    for (int mt = 0; mt < 4; ++mt) {
      u16x4 pk;
      #pragma unroll
      for (int r = 0; r < 4; ++r) pk[r] = f2bf(o_acc[t][mt][r] * inv);
      *(u16x4*)&O[(((size_t)b * S_ + q0 + t * 16 + l15) * H_ + h) * DH_ + mt * 16 + quad * 4] = pk;
    }
  }
}

// ---------------------------------------------------------------------------
extern "C" void kernel_launch(void* const* d_in, const int* in_sizes, int n_in,
                              void* d_out, int out_size, void* d_ws, size_t ws_size,
                              hipStream_t stream) {
  const float* x       = (const float*)d_in[0];
  const float* rot_cos = (const float*)d_in[1];
  const float* rot_sin = (const float*)d_in[2];
  const float* ln1_w   = (const float*)d_in[3];
  const float* w_qkv   = (const float*)d_in[4];
  const float* w_out   = (const float*)d_in[5];
  const float* ln2_w   = (const float*)d_in[6];
  const float* w_mlp1  = (const float*)d_in[7];
  const float* b_mlp1  = (const float*)d_in[8];
  const float* w_mlp2  = (const float*)d_in[9];
  const float* b_mlp2  = (const float*)d_in[10];
  float* out = (float*)d_out;

  char* wsb = (char*)d_ws;
  const size_t MB = 1u << 20;
  ushort_t* h1_bf  = (ushort_t*)(wsb + 0 * MB);    // 8 MB  (reused as h2)
  ushort_t* qkv_bf = (ushort_t*)(wsb + 8 * MB);    // 24 MB (V third unused)
  ushort_t* q_bf   = (ushort_t*)(wsb + 32 * MB);   // 8 MB
  ushort_t* k_bf   = (ushort_t*)(wsb + 40 * MB);   // 8 MB
  ushort_t* v_t    = (ushort_t*)(wsb + 48 * MB);   // 8 MB (B,H,Dh,S)
  ushort_t* o_bf   = (ushort_t*)(wsb + 56 * MB);   // 8 MB
  float*    x2     = (float*)   (wsb + 64 * MB);   // 16 MB
  ushort_t* u_bf   = (ushort_t*)(wsb + 80 * MB);   // 32 MB
  ushort_t* wq_bf  = (ushort_t*)(wsb + 112 * MB);  // 6 MB
  ushort_t* wo_bf  = (ushort_t*)(wsb + 118 * MB);  // 2 MB
  ushort_t* w1_bf  = (ushort_t*)(wsb + 120 * MB);  // 8 MB
  ushort_t* w2_bf  = (ushort_t*)(wsb + 128 * MB);  // 8 MB -> 136 MB total
  (void)ws_size; (void)in_sizes; (void)n_in; (void)out_size;

  dim3 b256(256);

  // 0) weights -> bf16
  cast_w_kernel<<<dim3(4096, 4), b256, 0, stream>>>(
      w_qkv, wq_bf, 3 * D_ * D_, w_out, wo_bf, D_ * D_,
      w_mlp1, w1_bf, MLP_ * D_, w_mlp2, w2_bf, MLP_ * D_);
  // 1) h1 = LN(x) * ln1_w -> bf16
  ln_kernel<<<dim3(ROWS_), b256, 0, stream>>>(x, ln1_w, h1_bf);
  // 2) qkv = h1 @ w_qkv^T; q,k -> qkv_bf, V -> v_t transposed (B,H,Dh,S)
  gemm_bt<0, 1, 1><<<dim3(3 * D_ / 128, ROWS_ / 128), b256, 0, stream>>>(
      h1_bf, wq_bf, nullptr, nullptr, qkv_bf, v_t, ROWS_, 3 * D_, D_);
  // 3) rope q,k -> (B,H,S,Dh) bf16
  rope_kernel<<<dim3(ROWS_), b256, 0, stream>>>(qkv_bf, rot_cos, rot_sin, q_bf, k_bf);
  // 4) flash attention -> o (B,S,H,Dh) bf16
  attn_kernel<<<dim3(16, B_ * H_), b256, 0, stream>>>(q_bf, k_bf, v_t, o_bf);
  // 5) x2 = x + o @ w_out^T -> fp32
  gemm_bt<4, 0, 0><<<dim3(D_ / 128, ROWS_ / 128), b256, 0, stream>>>(
      o_bf, wo_bf, nullptr, x, x2, nullptr, ROWS_, D_, D_);
  // 6) h2 = LN(x2) * ln2_w -> bf16
  ln_kernel<<<dim3(ROWS_), b256, 0, stream>>>(x2, ln2_w, h1_bf);
  // 7) u = gelu(h2 @ w_mlp1^T + b1) -> bf16
  gemm_bt<3, 1, 0><<<dim3(MLP_ / 128, ROWS_ / 128), b256, 0, stream>>>(
      h1_bf, w1_bf, b_mlp1, nullptr, u_bf, nullptr, ROWS_, MLP_, D_);
  // 8) out = x2 + u @ w_mlp2^T + b2 -> fp32
  gemm_bt<5, 0, 0><<<dim3(D_ / 128, ROWS_ / 128), b256, 0, stream>>>(
      u_bf, w2_bf, b_mlp2, x2, out, nullptr, ROWS_, D_, MLP_);
}

// Round 7
// 415.088 us; speedup vs baseline: 1.4544x; 1.0681x over previous
//
#include <hip/hip_runtime.h>
#include <hip/hip_bf16.h>
#include <math.h>

// ---------------------------------------------------------------------------
// DDiTBlockCausal: B=2, S=2048, D=1024, H=16, Dh=64, MLP=4096, fp32 I/O.
// Round 6: GEMM K-loop restructured: BK=64 (half the barrier drains),
// XOR-swizzled LDS chunks (conflict-free ds_read_b128 despite 128B row
// stride), XCD-rectangle block swizzle for L2 reuse. Attn/LN/rope from R5.
// ---------------------------------------------------------------------------

#define B_ 2
#define S_ 2048
#define D_ 1024
#define H_ 16
#define DH_ 64
#define MLP_ 4096
#define ROWS_ (B_ * S_)   // 4096

typedef short bf16x8 __attribute__((ext_vector_type(8)));
typedef float f32x4 __attribute__((ext_vector_type(4)));
typedef unsigned short ushort_t;
typedef ushort_t u16x4 __attribute__((ext_vector_type(4)));
typedef unsigned int u32x2 __attribute__((ext_vector_type(2)));

__device__ __forceinline__ float wave_reduce_sum(float v) {
  #pragma unroll
  for (int off = 32; off > 0; off >>= 1) v += __shfl_down(v, off, 64);
  return v;
}

__device__ __forceinline__ ushort_t f2bf(float v) {
  __hip_bfloat16 h = __float2bfloat16(v);
  return *(ushort_t*)&h;
}
__device__ __forceinline__ float bf2f(ushort_t u) {
  unsigned int v = ((unsigned int)u) << 16;
  union { unsigned int i; float f; } c; c.i = v; return c.f;
}

__device__ __forceinline__ void async_copy16(const void* g, void* l) {
  __builtin_amdgcn_global_load_lds(
      (const __attribute__((address_space(1))) void*)g,
      (__attribute__((address_space(3))) void*)l, 16, 0, 0);
}

// ---------------- weight cast fp32 -> bf16 (4 tensors, blockIdx.y picks) ---
__global__ __launch_bounds__(256) void cast_w_kernel(
    const float* __restrict__ s0, ushort_t* __restrict__ d0, int n0,
    const float* __restrict__ s1, ushort_t* __restrict__ d1, int n1,
    const float* __restrict__ s2, ushort_t* __restrict__ d2, int n2,
    const float* __restrict__ s3, ushort_t* __restrict__ d3, int n3) {
  const float* s; ushort_t* d; int n;
  switch (blockIdx.y) {
    case 0: s = s0; d = d0; n = n0; break;
    case 1: s = s1; d = d1; n = n1; break;
    case 2: s = s2; d = d2; n = n2; break;
    default: s = s3; d = d3; n = n3; break;
  }
  const int i = (blockIdx.x * 256 + threadIdx.x) * 4;
  if (i < n) {
    const float4 v = *reinterpret_cast<const float4*>(s + i);
    u16x4 o;
    o[0] = f2bf(v.x); o[1] = f2bf(v.y); o[2] = f2bf(v.z); o[3] = f2bf(v.w);
    *reinterpret_cast<u16x4*>(d + i) = o;
  }
}

// ---------------- LayerNorm: fp32 in, bf16 out -----------------------------
__global__ __launch_bounds__(256) void ln_kernel(
    const float* __restrict__ x, const float* __restrict__ w,
    ushort_t* __restrict__ y) {
  const int row = blockIdx.x;
  const float4 v = reinterpret_cast<const float4*>(x + (size_t)row * D_)[threadIdx.x];
  float s  = v.x + v.y + v.z + v.w;
  float ss = v.x * v.x + v.y * v.y + v.z * v.z + v.w * v.w;
  __shared__ float red[8];
  const int wave = threadIdx.x >> 6, lane = threadIdx.x & 63;
  const float ws1 = wave_reduce_sum(s);
  const float ws2 = wave_reduce_sum(ss);
  if (lane == 0) { red[wave] = ws1; red[4 + wave] = ws2; }
  __syncthreads();
  const float tot  = red[0] + red[1] + red[2] + red[3];
  const float tot2 = red[4] + red[5] + red[6] + red[7];
  const float mu  = tot * (1.0f / D_);
  const float var = tot2 * (1.0f / D_) - mu * mu;
  const float inv = rsqrtf(var + 1e-5f);
  const float4 wv = reinterpret_cast<const float4*>(w)[threadIdx.x];
  u16x4 o;
  o[0] = f2bf((v.x - mu) * inv * wv.x);
  o[1] = f2bf((v.y - mu) * inv * wv.y);
  o[2] = f2bf((v.z - mu) * inv * wv.z);
  o[3] = f2bf((v.w - mu) * inv * wv.w);
  reinterpret_cast<u16x4*>(y + (size_t)row * D_)[threadIdx.x] = o;
}

// ---------------- bf16 MFMA GEMM: C[M,N] = A[M,K] * W[N,K]^T ---------------
// 128x128 tile, 4 waves, BK=64, XOR-swizzled LDS, XCD-rect block swizzle.
// FUSE bits: 1=+bias, 2=gelu, 4=+res (fp32). QKV=1: V cols -> Vt transposed.
__device__ __forceinline__ float gelu_tanh(float u) {
  const float u3 = u * u * u;
  const float t = tanhf(0.7978845608028654f * (u + 0.044715f * u3));
  return 0.5f * u * (1.0f + t);
}

template <int FUSE, int OUTBF, int QKV>
__global__ __launch_bounds__(256) void gemm_bt(
    const ushort_t* __restrict__ A, const ushort_t* __restrict__ W,
    const float* __restrict__ bias, const float* __restrict__ res,
    void* __restrict__ Cv, ushort_t* __restrict__ VtOut,
    int M, int N, int K, int sm, int sn, int rects_n) {
  __shared__ ushort_t As[128 * 64];   // 16 KB
  __shared__ ushort_t Bs[128 * 64];   // 16 KB
  const int tid = threadIdx.x;
  const int wave = tid >> 6, lane = tid & 63;
  const int l15 = lane & 15, quad = lane >> 4;

  // XCD-rectangle swizzle: lin&7 ~ XCD; each XCD owns an sm x sn tile rect.
  const int lin = blockIdx.x;
  const int xcd = lin & 7, j = lin >> 3;
  const int rm = xcd / rects_n, rn = xcd % rects_n;
  const int m0 = (rm * sm + (j % sm)) * 128;
  const int n0 = (rn * sn + (j / sm)) * 128;
  const int wm = (wave & 1) * 64, wn = (wave >> 1) * 64;

  // Staging map (XOR chunk swizzle): LDS slot L=i*256+tid holds global chunk
  // (row = i*32 + (tid>>3), c8 = (tid&7) ^ ((tid>>3)&7)).
  const int srow = tid >> 3;                       // 0..31 (+ i*32)
  const int scol = (((tid & 7) ^ (srow & 7)) * 8); // swizzled source col
  const ushort_t* Ag = A + (size_t)(m0 + srow) * K + scol;
  const ushort_t* Wg = W + (size_t)(n0 + srow) * K + scol;

  f32x4 acc[4][4] = {};
  const int sw = l15 & 7;                          // read-side row xor

  for (int k0 = 0; k0 < K; k0 += 64) {
    __syncthreads();
    #pragma unroll
    for (int i = 0; i < 4; ++i) {
      async_copy16(Ag + (size_t)i * 32 * K + k0, &As[i * 2048 + tid * 8]);
      async_copy16(Wg + (size_t)i * 32 * K + k0, &Bs[i * 2048 + tid * 8]);
    }
    __syncthreads();

    #pragma unroll
    for (int kk = 0; kk < 2; ++kk) {
      bf16x8 af[4], bfr[4];
      #pragma unroll
      for (int i = 0; i < 4; ++i) {
        const int slot = ((kk * 4 + quad) ^ sw) * 8;
        af[i]  = *(const bf16x8*)&As[(wm + i * 16 + l15) * 64 + slot];
        bfr[i] = *(const bf16x8*)&Bs[(wn + i * 16 + l15) * 64 + slot];
      }
      #pragma unroll
      for (int i = 0; i < 4; ++i)
        #pragma unroll
        for (int jj = 0; jj < 4; ++jj)
          acc[i][jj] = __builtin_amdgcn_mfma_f32_16x16x32_bf16(af[i], bfr[jj], acc[i][jj], 0, 0, 0);
    }
  }

  #pragma unroll
  for (int i = 0; i < 4; ++i) {
    const int mb = m0 + wm + i * 16 + quad * 4;     // + r
    #pragma unroll
    for (int jj = 0; jj < 4; ++jj) {
      const int n = n0 + wn + jj * 16 + l15;
      float cv[4];
      #pragma unroll
      for (int r = 0; r < 4; ++r) {
        float c = acc[i][jj][r];
        if (FUSE & 1) c += bias[n];
        if (FUSE & 2) c = gelu_tanh(c);
        if (FUSE & 4) c += res[(size_t)(mb + r) * N + n];
        cv[r] = c;
      }
      if (QKV && ((n0 + wn) >> 10) == 2) {
        // V part: transposed bf16 store to Vt (B,H,Dh,S)
        const int d  = n & 63;
        const int hh = (n >> 6) & 15;
        const int bb = mb >> 11;
        const int ss = mb & (S_ - 1);
        u16x4 pk;
        #pragma unroll
        for (int r = 0; r < 4; ++r) pk[r] = f2bf(cv[r]);
        *(u16x4*)&VtOut[((size_t)(bb * H_ + hh) * DH_ + d) * S_ + ss] = pk;
      } else {
        #pragma unroll
        for (int r = 0; r < 4; ++r) {
          if (OUTBF) ((ushort_t*)Cv)[(size_t)(mb + r) * N + n] = f2bf(cv[r]);
          else       ((float*)Cv)[(size_t)(mb + r) * N + n]   = cv[r];
        }
      }
    }
  }
}

// ---------------- RoPE (q,k only) + transpose to (B,H,S,Dh), bf16 ---------
// Q pre-scaled by 1/sqrt(Dh) = 0.125 (exact in bf16).
__global__ __launch_bounds__(256) void rope_kernel(
    const ushort_t* __restrict__ qkv, const float* __restrict__ cosb,
    const float* __restrict__ sinb, ushort_t* __restrict__ Qo,
    ushort_t* __restrict__ Ko) {
  const int bs = blockIdx.x;           // b*S + s
  const int s  = bs & (S_ - 1);
  const int b  = bs >> 11;
  const int t  = threadIdx.x;
  const ushort_t* base = qkv + (size_t)bs * (3 * D_);
  #pragma unroll
  for (int i = 0; i < 8; ++i) {        // q,k only: e in [0, 2048)
    const int e = i * 256 + t;
    const int which = e >> 10;         // 0=q, 1=k
    const int rem = e & 1023;
    const int h = rem >> 6;
    const int d = rem & 63;
    const float val = bf2f(base[e]);
    float out;
    if (d < 32) {
      out = val * cosb[s * 64 + d] - bf2f(base[e + 32]) * sinb[s * 64 + d];
    } else {
      out = val * cosb[s * 64 + d - 32] + bf2f(base[e - 32]) * sinb[s * 64 + d - 32];
    }
    const size_t oidx = (((size_t)(b * H_ + h)) * S_ + s) * DH_ + d;
    if (which == 0) Qo[oidx] = f2bf(out * 0.125f);
    else            Ko[oidx] = f2bf(out);
  }
}

// ---------------- Wave-autonomous transposed flash attention ---------------
// Q,K bf16 (B,H,S,Dh); Vt bf16 (B,H,Dh,S); O bf16 (B,S,H,Dh).
// One wave = 32 queries (2 q-tiles sharing each K/V fragment), no barriers.
#define PPAD 72

__global__ __launch_bounds__(256) void attn_kernel(
    const ushort_t* __restrict__ Qb, const ushort_t* __restrict__ Kb,
    const ushort_t* __restrict__ Vt, ushort_t* __restrict__ O) {
  const int wave = threadIdx.x >> 6;
  const int lane = threadIdx.x & 63;
  const int l15 = lane & 15, quad = lane >> 4;
  const int bh = blockIdx.y;
  const int b = bh >> 4, h = bh & 15;
  const int wl = blockIdx.x * 4 + wave;            // 0..63 per bh
  const int g  = (wl & 1) ? (63 - (wl >> 1)) : (wl >> 1);
  const int q0 = g * 32;

  __shared__ ushort_t Plds[4][2][16 * PPAD];

  const ushort_t* Kbh = Kb + (size_t)bh * S_ * DH_;
  const ushort_t* Vbh = Vt + (size_t)bh * DH_ * S_;

  // Q B-fragments for both 16-query tiles
  bf16x8 qb[2][2];
  #pragma unroll
  for (int t = 0; t < 2; ++t) {
    const ushort_t* qptr = Qb + ((size_t)bh * S_ + q0 + t * 16 + l15) * DH_ + quad * 8;
    qb[t][0] = *(const bf16x8*)(qptr);
    qb[t][1] = *(const bf16x8*)(qptr + 32);
  }

  f32x4 o_acc[2][4] = {};              // [tile][dh-mt]; O^T layout
  float m_run[2] = {-1e30f, -1e30f}, l_run[2] = {0.0f, 0.0f};

  const int nch = (q0 >> 6) + 1;       // 64-key chunks (covers q0+31)

  // preload K fragments for chunk 0
  bf16x8 ka[4][2];
  #pragma unroll
  for (int kt = 0; kt < 4; ++kt) {
    const ushort_t* kp = Kbh + (size_t)(kt * 16 + l15) * DH_ + quad * 8;
    ka[kt][0] = *(const bf16x8*)kp;
    ka[kt][1] = *(const bf16x8*)(kp + 32);
  }

  for (int c = 0; c < nch; ++c) {
    const int k0 = c << 6;

    // V^T A-fragments for this chunk — issue first (consumed at end of body)
    bf16x8 va[4][2];
    #pragma unroll
    for (int mt = 0; mt < 4; ++mt) {
      const ushort_t* vp = Vbh + (size_t)(mt * 16 + l15) * S_ + k0 + quad * 8;
      va[mt][0] = *(const bf16x8*)vp;
      va[mt][1] = *(const bf16x8*)(vp + 32);
    }

    // S^T = K Q^T for both tiles
    f32x4 st[2][4];
    #pragma unroll
    for (int t = 0; t < 2; ++t)
      #pragma unroll
      for (int kt = 0; kt < 4; ++kt) {
        f32x4 z = {0.0f, 0.0f, 0.0f, 0.0f};
        z = __builtin_amdgcn_mfma_f32_16x16x32_bf16(ka[kt][0], qb[t][0], z, 0, 0, 0);
        z = __builtin_amdgcn_mfma_f32_16x16x32_bf16(ka[kt][1], qb[t][1], z, 0, 0, 0);
        st[t][kt] = z;
      }

    // prefetch next chunk's K fragments (hidden under softmax + PV)
    if (c + 1 < nch) {
      const int k1 = (c + 1) << 6;
      bf16x8 kan[4][2];
      #pragma unroll
      for (int kt = 0; kt < 4; ++kt) {
        const ushort_t* kp = Kbh + (size_t)(k1 + kt * 16 + l15) * DH_ + quad * 8;
        kan[kt][0] = *(const bf16x8*)kp;
        kan[kt][1] = *(const bf16x8*)(kp + 32);
      }
      #pragma unroll
      for (int kt = 0; kt < 4; ++kt) { ka[kt][0] = kan[kt][0]; ka[kt][1] = kan[kt][1]; }
    }

    // causal mask in the diagonal chunk
    if (c == nch - 1) {
      #pragma unroll
      for (int t = 0; t < 2; ++t) {
        const int query = q0 + t * 16 + l15;
        #pragma unroll
        for (int kt = 0; kt < 4; ++kt)
          #pragma unroll
          for (int r = 0; r < 4; ++r)
            if (k0 + kt * 16 + quad * 4 + r > query) st[t][kt][r] = -1e30f;
      }
    }

    // online softmax per tile (per-lane stats, 2 shuffles per reduction)
    #pragma unroll
    for (int t = 0; t < 2; ++t) {
      float mx = -1e30f;
      #pragma unroll
      for (int kt = 0; kt < 4; ++kt)
        #pragma unroll
        for (int r = 0; r < 4; ++r) mx = fmaxf(mx, st[t][kt][r]);
      mx = fmaxf(mx, __shfl_xor(mx, 16, 64));
      mx = fmaxf(mx, __shfl_xor(mx, 32, 64));
      const float m_new = fmaxf(m_run[t], mx);
      const float alpha = __expf(m_run[t] - m_new);
      float rs = 0.0f;
      #pragma unroll
      for (int kt = 0; kt < 4; ++kt)
        #pragma unroll
        for (int r = 0; r < 4; ++r) {
          const float e = __expf(st[t][kt][r] - m_new);
          st[t][kt][r] = e;
          rs += e;
        }
      rs += __shfl_xor(rs, 16, 64);
      rs += __shfl_xor(rs, 32, 64);
      l_run[t] = l_run[t] * alpha + rs;
      m_run[t] = m_new;
      #pragma unroll
      for (int mt = 0; mt < 4; ++mt)
        #pragma unroll
        for (int r = 0; r < 4; ++r) o_acc[t][mt][r] *= alpha;
    }

    // P^T transform (C-layout -> LDS -> B-fragment) and PV per tile
    #pragma unroll
    for (int t = 0; t < 2; ++t) {
      ushort_t* Pw = &Plds[wave][t][0];
      #pragma unroll
      for (int kt = 0; kt < 4; ++kt) {
        u32x2 wpair;
        wpair[0] = (unsigned)f2bf(st[t][kt][0]) | ((unsigned)f2bf(st[t][kt][1]) << 16);
        wpair[1] = (unsigned)f2bf(st[t][kt][2]) | ((unsigned)f2bf(st[t][kt][3]) << 16);
        *(u32x2*)&Pw[l15 * PPAD + kt * 16 + quad * 4] = wpair;
      }
      asm volatile("s_waitcnt lgkmcnt(0)" ::: "memory");
      const bf16x8 pb0 = *(const bf16x8*)&Pw[l15 * PPAD + quad * 8];
      const bf16x8 pb1 = *(const bf16x8*)&Pw[l15 * PPAD + 32 + quad * 8];
      #pragma unroll
      for (int mt = 0; mt < 4; ++mt) {
        o_acc[t][mt] = __builtin_amdgcn_mfma_f32_16x16x32_bf16(va[mt][0], pb0, o_acc[t][mt], 0, 0, 0);
        o_acc[t][mt] = __builtin_amdgcn_mfma_f32_16x16x32_bf16(va[mt][1], pb1, o_acc[t][mt], 0, 0, 0);
      }
    }
  }

  // epilogue: normalize, store bf16 to (B,S,H,Dh)
  #pragma unroll
  for (int t = 0; t < 2; ++t) {
    const float inv = 1.0f / l_run[t];
    #pragma unroll
    for (int mt = 0; mt < 4; ++mt) {
      u16x4 pk;
      #pragma unroll
      for (int r = 0; r < 4; ++r) pk[r] = f2bf(o_acc[t][mt][r] * inv);
      *(u16x4*)&O[(((size_t)b * S_ + q0 + t * 16 + l15) * H_ + h) * DH_ + mt * 16 + quad * 4] = pk;
    }
  }
}

// ---------------------------------------------------------------------------
extern "C" void kernel_launch(void* const* d_in, const int* in_sizes, int n_in,
                              void* d_out, int out_size, void* d_ws, size_t ws_size,
                              hipStream_t stream) {
  const float* x       = (const float*)d_in[0];
  const float* rot_cos = (const float*)d_in[1];
  const float* rot_sin = (const float*)d_in[2];
  const float* ln1_w   = (const float*)d_in[3];
  const float* w_qkv   = (const float*)d_in[4];
  const float* w_out   = (const float*)d_in[5];
  const float* ln2_w   = (const float*)d_in[6];
  const float* w_mlp1  = (const float*)d_in[7];
  const float* b_mlp1  = (const float*)d_in[8];
  const float* w_mlp2  = (const float*)d_in[9];
  const float* b_mlp2  = (const float*)d_in[10];
  float* out = (float*)d_out;

  char* wsb = (char*)d_ws;
  const size_t MB = 1u << 20;
  ushort_t* h1_bf  = (ushort_t*)(wsb + 0 * MB);    // 8 MB  (reused as h2)
  ushort_t* qkv_bf = (ushort_t*)(wsb + 8 * MB);    // 24 MB (V third unused)
  ushort_t* q_bf   = (ushort_t*)(wsb + 32 * MB);   // 8 MB
  ushort_t* k_bf   = (ushort_t*)(wsb + 40 * MB);   // 8 MB
  ushort_t* v_t    = (ushort_t*)(wsb + 48 * MB);   // 8 MB (B,H,Dh,S)
  ushort_t* o_bf   = (ushort_t*)(wsb + 56 * MB);   // 8 MB
  float*    x2     = (float*)   (wsb + 64 * MB);   // 16 MB
  ushort_t* u_bf   = (ushort_t*)(wsb + 80 * MB);   // 32 MB
  ushort_t* wq_bf  = (ushort_t*)(wsb + 112 * MB);  // 6 MB
  ushort_t* wo_bf  = (ushort_t*)(wsb + 118 * MB);  // 2 MB
  ushort_t* w1_bf  = (ushort_t*)(wsb + 120 * MB);  // 8 MB
  ushort_t* w2_bf  = (ushort_t*)(wsb + 128 * MB);  // 8 MB -> 136 MB total
  (void)ws_size; (void)in_sizes; (void)n_in; (void)out_size;

  dim3 b256(256);

  // 0) weights -> bf16
  cast_w_kernel<<<dim3(4096, 4), b256, 0, stream>>>(
      w_qkv, wq_bf, 3 * D_ * D_, w_out, wo_bf, D_ * D_,
      w_mlp1, w1_bf, MLP_ * D_, w_mlp2, w2_bf, MLP_ * D_);
  // 1) h1 = LN(x) * ln1_w -> bf16
  ln_kernel<<<dim3(ROWS_), b256, 0, stream>>>(x, ln1_w, h1_bf);
  // 2) qkv = h1 @ w_qkv^T; q,k -> qkv_bf, V -> v_t transposed (B,H,Dh,S)
  //    gm=32, gn=24 -> rects 2x4, sm=16, sn=6, blocks=768
  gemm_bt<0, 1, 1><<<dim3(768), b256, 0, stream>>>(
      h1_bf, wq_bf, nullptr, nullptr, qkv_bf, v_t, ROWS_, 3 * D_, D_, 16, 6, 4);
  // 3) rope q,k -> (B,H,S,Dh) bf16
  rope_kernel<<<dim3(ROWS_), b256, 0, stream>>>(qkv_bf, rot_cos, rot_sin, q_bf, k_bf);
  // 4) flash attention -> o (B,S,H,Dh) bf16
  attn_kernel<<<dim3(16, B_ * H_), b256, 0, stream>>>(q_bf, k_bf, v_t, o_bf);
  // 5) x2 = x + o @ w_out^T -> fp32   gm=32, gn=8 -> rects 4x2, sm=8, sn=4
  gemm_bt<4, 0, 0><<<dim3(256), b256, 0, stream>>>(
      o_bf, wo_bf, nullptr, x, x2, nullptr, ROWS_, D_, D_, 8, 4, 2);
  // 6) h2 = LN(x2) * ln2_w -> bf16
  ln_kernel<<<dim3(ROWS_), b256, 0, stream>>>(x2, ln2_w, h1_bf);
  // 7) u = gelu(h2 @ w_mlp1^T + b1) -> bf16  gm=32, gn=32 -> rects 2x4, sm=16, sn=8
  gemm_bt<3, 1, 0><<<dim3(1024), b256, 0, stream>>>(
      h1_bf, w1_bf, b_mlp1, nullptr, u_bf, nullptr, ROWS_, MLP_, D_, 16, 8, 4);
  // 8) out = x2 + u @ w_mlp2^T + b2 -> fp32  gm=32, gn=8 -> rects 4x2, sm=8, sn=4
  gemm_bt<5, 0, 0><<<dim3(256), b256, 0, stream>>>(
      u_bf, w2_bf, b_mlp2, x2, out, nullptr, ROWS_, D_, MLP_, 8, 4, 2);
}

// Round 8
// 388.077 us; speedup vs baseline: 1.5557x; 1.0696x over previous
//
#include <hip/hip_runtime.h>
#include <hip/hip_bf16.h>
#include <math.h>

// ---------------------------------------------------------------------------
// DDiTBlockCausal: B=2, S=2048, D=1024, H=16, Dh=64, MLP=4096, fp32 I/O.
// Round 7: GEMMs get 2-stage LDS double-buffering (loads drain with one full
// iteration of slack instead of zero). N=1024 GEMMs move to a 64x128 tile
// (512 blocks = 2/CU instead of 1/CU). XOR swizzles per geometry; XCD-rect
// block swizzle kept. Attn/LN/rope unchanged from R6 (passing, verified).
// ---------------------------------------------------------------------------

#define B_ 2
#define S_ 2048
#define D_ 1024
#define H_ 16
#define DH_ 64
#define MLP_ 4096
#define ROWS_ (B_ * S_)   // 4096

typedef short bf16x8 __attribute__((ext_vector_type(8)));
typedef float f32x4 __attribute__((ext_vector_type(4)));
typedef unsigned short ushort_t;
typedef ushort_t u16x4 __attribute__((ext_vector_type(4)));
typedef unsigned int u32x2 __attribute__((ext_vector_type(2)));

__device__ __forceinline__ float wave_reduce_sum(float v) {
  #pragma unroll
  for (int off = 32; off > 0; off >>= 1) v += __shfl_down(v, off, 64);
  return v;
}

__device__ __forceinline__ ushort_t f2bf(float v) {
  __hip_bfloat16 h = __float2bfloat16(v);
  return *(ushort_t*)&h;
}
__device__ __forceinline__ float bf2f(ushort_t u) {
  unsigned int v = ((unsigned int)u) << 16;
  union { unsigned int i; float f; } c; c.i = v; return c.f;
}

__device__ __forceinline__ void async_copy16(const void* g, void* l) {
  __builtin_amdgcn_global_load_lds(
      (const __attribute__((address_space(1))) void*)g,
      (__attribute__((address_space(3))) void*)l, 16, 0, 0);
}

// ---------------- weight cast fp32 -> bf16 (4 tensors, blockIdx.y picks) ---
__global__ __launch_bounds__(256) void cast_w_kernel(
    const float* __restrict__ s0, ushort_t* __restrict__ d0, int n0,
    const float* __restrict__ s1, ushort_t* __restrict__ d1, int n1,
    const float* __restrict__ s2, ushort_t* __restrict__ d2, int n2,
    const float* __restrict__ s3, ushort_t* __restrict__ d3, int n3) {
  const float* s; ushort_t* d; int n;
  switch (blockIdx.y) {
    case 0: s = s0; d = d0; n = n0; break;
    case 1: s = s1; d = d1; n = n1; break;
    case 2: s = s2; d = d2; n = n2; break;
    default: s = s3; d = d3; n = n3; break;
  }
  const int i = (blockIdx.x * 256 + threadIdx.x) * 4;
  if (i < n) {
    const float4 v = *reinterpret_cast<const float4*>(s + i);
    u16x4 o;
    o[0] = f2bf(v.x); o[1] = f2bf(v.y); o[2] = f2bf(v.z); o[3] = f2bf(v.w);
    *reinterpret_cast<u16x4*>(d + i) = o;
  }
}

// ---------------- LayerNorm: fp32 in, bf16 out -----------------------------
__global__ __launch_bounds__(256) void ln_kernel(
    const float* __restrict__ x, const float* __restrict__ w,
    ushort_t* __restrict__ y) {
  const int row = blockIdx.x;
  const float4 v = reinterpret_cast<const float4*>(x + (size_t)row * D_)[threadIdx.x];
  float s  = v.x + v.y + v.z + v.w;
  float ss = v.x * v.x + v.y * v.y + v.z * v.z + v.w * v.w;
  __shared__ float red[8];
  const int wave = threadIdx.x >> 6, lane = threadIdx.x & 63;
  const float ws1 = wave_reduce_sum(s);
  const float ws2 = wave_reduce_sum(ss);
  if (lane == 0) { red[wave] = ws1; red[4 + wave] = ws2; }
  __syncthreads();
  const float tot  = red[0] + red[1] + red[2] + red[3];
  const float tot2 = red[4] + red[5] + red[6] + red[7];
  const float mu  = tot * (1.0f / D_);
  const float var = tot2 * (1.0f / D_) - mu * mu;
  const float inv = rsqrtf(var + 1e-5f);
  const float4 wv = reinterpret_cast<const float4*>(w)[threadIdx.x];
  u16x4 o;
  o[0] = f2bf((v.x - mu) * inv * wv.x);
  o[1] = f2bf((v.y - mu) * inv * wv.y);
  o[2] = f2bf((v.z - mu) * inv * wv.z);
  o[3] = f2bf((v.w - mu) * inv * wv.w);
  reinterpret_cast<u16x4*>(y + (size_t)row * D_)[threadIdx.x] = o;
}

__device__ __forceinline__ float gelu_tanh(float u) {
  const float u3 = u * u * u;
  const float t = tanhf(0.7978845608028654f * (u + 0.044715f * u3));
  return 0.5f * u * (1.0f + t);
}

// ---------------- bf16 MFMA GEMM 128x128, BK=32, 2-stage dbuf --------------
// C[M,N] = A[M,K] * W[N,K]^T. FUSE bits: 1=+bias, 2=gelu, 4=+res (fp32).
// QKV=1: cols n>=2048 (V) stored transposed to Vt (B,H,Dh,S).
template <int FUSE, int OUTBF, int QKV>
__global__ __launch_bounds__(256) void gemm_bt(
    const ushort_t* __restrict__ A, const ushort_t* __restrict__ W,
    const float* __restrict__ bias, const float* __restrict__ res,
    void* __restrict__ Cv, ushort_t* __restrict__ VtOut,
    int M, int N, int K, int sm, int sn, int rects_n) {
  __shared__ ushort_t As[2][128 * 32];   // 8 KB / stage
  __shared__ ushort_t Bs[2][128 * 32];   // 8 KB / stage  -> 32 KB total
  const int tid = threadIdx.x;
  const int wave = tid >> 6, lane = tid & 63;
  const int l15 = lane & 15, quad = lane >> 4;

  // XCD-rectangle swizzle
  const int lin = blockIdx.x;
  const int xcd = lin & 7, j = lin >> 3;
  const int rm = xcd / rects_n, rn = xcd % rects_n;
  const int m0 = (rm * sm + (j % sm)) * 128;
  const int n0 = (rn * sn + (j / sm)) * 128;
  const int wm = (wave & 1) * 64, wn = (wave >> 1) * 64;

  // Staging: row = tid>>2 (+64), chunk-of-8 swizzled by row&3.
  const int srow = tid >> 2;                        // 0..63
  const int gcol = (((tid & 3) ^ (srow & 3)) * 8);  // swizzled source col
  const ushort_t* Ag = A + (size_t)(m0 + srow) * K + gcol;
  const ushort_t* Wg = W + (size_t)(n0 + srow) * K + gcol;

  f32x4 acc[4][4] = {};
  const int rslot = (quad ^ (l15 & 3)) * 8;         // read-side swizzle

  const int NI = K >> 5;
  // prologue: stage 0
  async_copy16(Ag,          &As[0][tid * 8]);
  async_copy16(Ag + 64 * K, &As[0][2048 + tid * 8]);
  async_copy16(Wg,          &Bs[0][tid * 8]);
  async_copy16(Wg + 64 * K, &Bs[0][2048 + tid * 8]);

  for (int i = 0; i < NI; ++i) {
    const int st = i & 1;
    __syncthreads();                   // drains prefetch issued last iter
    if (i + 1 < NI) {
      const int k1 = (i + 1) << 5;
      async_copy16(Ag + k1,          &As[1 - st][tid * 8]);
      async_copy16(Ag + 64 * K + k1, &As[1 - st][2048 + tid * 8]);
      async_copy16(Wg + k1,          &Bs[1 - st][tid * 8]);
      async_copy16(Wg + 64 * K + k1, &Bs[1 - st][2048 + tid * 8]);
    }
    bf16x8 af[4], bfr[4];
    #pragma unroll
    for (int ii = 0; ii < 4; ++ii) {
      af[ii]  = *(const bf16x8*)&As[st][(wm + ii * 16 + l15) * 32 + rslot];
      bfr[ii] = *(const bf16x8*)&Bs[st][(wn + ii * 16 + l15) * 32 + rslot];
    }
    #pragma unroll
    for (int ii = 0; ii < 4; ++ii)
      #pragma unroll
      for (int jj = 0; jj < 4; ++jj)
        acc[ii][jj] = __builtin_amdgcn_mfma_f32_16x16x32_bf16(af[ii], bfr[jj], acc[ii][jj], 0, 0, 0);
  }

  #pragma unroll
  for (int i = 0; i < 4; ++i) {
    const int mb = m0 + wm + i * 16 + quad * 4;     // + r
    #pragma unroll
    for (int jj = 0; jj < 4; ++jj) {
      const int n = n0 + wn + jj * 16 + l15;
      float cv[4];
      #pragma unroll
      for (int r = 0; r < 4; ++r) {
        float c = acc[i][jj][r];
        if (FUSE & 1) c += bias[n];
        if (FUSE & 2) c = gelu_tanh(c);
        if (FUSE & 4) c += res[(size_t)(mb + r) * N + n];
        cv[r] = c;
      }
      if (QKV && ((n0 + wn) >> 10) == 2) {
        const int d  = n & 63;
        const int hh = (n >> 6) & 15;
        const int bb = mb >> 11;
        const int ss = mb & (S_ - 1);
        u16x4 pk;
        #pragma unroll
        for (int r = 0; r < 4; ++r) pk[r] = f2bf(cv[r]);
        *(u16x4*)&VtOut[((size_t)(bb * H_ + hh) * DH_ + d) * S_ + ss] = pk;
      } else {
        #pragma unroll
        for (int r = 0; r < 4; ++r) {
          if (OUTBF) ((ushort_t*)Cv)[(size_t)(mb + r) * N + n] = f2bf(cv[r]);
          else       ((float*)Cv)[(size_t)(mb + r) * N + n]   = cv[r];
        }
      }
    }
  }
}

// ---------------- bf16 MFMA GEMM 64x128, BK=64, 2-stage dbuf ---------------
// For N=1024 GEMMs (outproj, mlp2): 512 blocks instead of 256.
template <int FUSE, int OUTBF>
__global__ __launch_bounds__(256) void gemm64_bt(
    const ushort_t* __restrict__ A, const ushort_t* __restrict__ W,
    const float* __restrict__ bias, const float* __restrict__ res,
    void* __restrict__ Cv, int M, int N, int K, int sm, int sn, int rects_n) {
  __shared__ ushort_t As[2][64 * 64];    // 8 KB / stage
  __shared__ ushort_t Bs[2][128 * 64];   // 16 KB / stage -> 48 KB total
  const int tid = threadIdx.x;
  const int wave = tid >> 6, lane = tid & 63;
  const int l15 = lane & 15, quad = lane >> 4;

  const int lin = blockIdx.x;
  const int xcd = lin & 7, j = lin >> 3;
  const int rm = xcd / rects_n, rn = xcd % rects_n;
  const int m0 = (rm * sm + (j % sm)) * 64;
  const int n0 = (rn * sn + (j / sm)) * 128;
  const int wn = wave * 32;

  // Staging: row = tid>>3 (+32k), chunk-of-8 swizzled by row&7 (as R6).
  const int srow = tid >> 3;                        // 0..31
  const int gcol = (((tid & 7) ^ (srow & 7)) * 8);
  const ushort_t* Ag = A + (size_t)(m0 + srow) * K + gcol;
  const ushort_t* Wg = W + (size_t)(n0 + srow) * K + gcol;

  f32x4 acc[4][2] = {};

  const int NI = K >> 6;
  #pragma unroll
  for (int i = 0; i < 2; ++i)
    async_copy16(Ag + (size_t)i * 32 * K, &As[0][i * 2048 + tid * 8]);
  #pragma unroll
  for (int i = 0; i < 4; ++i)
    async_copy16(Wg + (size_t)i * 32 * K, &Bs[0][i * 2048 + tid * 8]);

  for (int it = 0; it < NI; ++it) {
    const int st = it & 1;
    __syncthreads();
    if (it + 1 < NI) {
      const int k1 = (it + 1) << 6;
      #pragma unroll
      for (int i = 0; i < 2; ++i)
        async_copy16(Ag + (size_t)i * 32 * K + k1, &As[1 - st][i * 2048 + tid * 8]);
      #pragma unroll
      for (int i = 0; i < 4; ++i)
        async_copy16(Wg + (size_t)i * 32 * K + k1, &Bs[1 - st][i * 2048 + tid * 8]);
    }
    #pragma unroll
    for (int kk = 0; kk < 2; ++kk) {
      const int slot = (((kk * 4 + quad) ^ (l15 & 7)) * 8);
      bf16x8 af[4], bfr[2];
      #pragma unroll
      for (int i = 0; i < 4; ++i)
        af[i] = *(const bf16x8*)&As[st][(i * 16 + l15) * 64 + slot];
      #pragma unroll
      for (int jj = 0; jj < 2; ++jj)
        bfr[jj] = *(const bf16x8*)&Bs[st][(wn + jj * 16 + l15) * 64 + slot];
      #pragma unroll
      for (int i = 0; i < 4; ++i)
        #pragma unroll
        for (int jj = 0; jj < 2; ++jj)
          acc[i][jj] = __builtin_amdgcn_mfma_f32_16x16x32_bf16(af[i], bfr[jj], acc[i][jj], 0, 0, 0);
    }
  }

  #pragma unroll
  for (int i = 0; i < 4; ++i) {
    const int mb = m0 + i * 16 + quad * 4;          // + r
    #pragma unroll
    for (int jj = 0; jj < 2; ++jj) {
      const int n = n0 + wn + jj * 16 + l15;
      #pragma unroll
      for (int r = 0; r < 4; ++r) {
        float c = acc[i][jj][r];
        if (FUSE & 1) c += bias[n];
        if (FUSE & 2) c = gelu_tanh(c);
        if (FUSE & 4) c += res[(size_t)(mb + r) * N + n];
        if (OUTBF) ((ushort_t*)Cv)[(size_t)(mb + r) * N + n] = f2bf(c);
        else       ((float*)Cv)[(size_t)(mb + r) * N + n]   = c;
      }
    }
  }
}

// ---------------- RoPE (q,k only) + transpose to (B,H,S,Dh), bf16 ---------
__global__ __launch_bounds__(256) void rope_kernel(
    const ushort_t* __restrict__ qkv, const float* __restrict__ cosb,
    const float* __restrict__ sinb, ushort_t* __restrict__ Qo,
    ushort_t* __restrict__ Ko) {
  const int bs = blockIdx.x;           // b*S + s
  const int s  = bs & (S_ - 1);
  const int b  = bs >> 11;
  const int t  = threadIdx.x;
  const ushort_t* base = qkv + (size_t)bs * (3 * D_);
  #pragma unroll
  for (int i = 0; i < 8; ++i) {        // q,k only: e in [0, 2048)
    const int e = i * 256 + t;
    const int which = e >> 10;         // 0=q, 1=k
    const int rem = e & 1023;
    const int h = rem >> 6;
    const int d = rem & 63;
    const float val = bf2f(base[e]);
    float out;
    if (d < 32) {
      out = val * cosb[s * 64 + d] - bf2f(base[e + 32]) * sinb[s * 64 + d];
    } else {
      out = val * cosb[s * 64 + d - 32] + bf2f(base[e - 32]) * sinb[s * 64 + d - 32];
    }
    const size_t oidx = (((size_t)(b * H_ + h)) * S_ + s) * DH_ + d;
    if (which == 0) Qo[oidx] = f2bf(out * 0.125f);
    else            Ko[oidx] = f2bf(out);
  }
}

// ---------------- Wave-autonomous transposed flash attention ---------------
#define PPAD 72

__global__ __launch_bounds__(256) void attn_kernel(
    const ushort_t* __restrict__ Qb, const ushort_t* __restrict__ Kb,
    const ushort_t* __restrict__ Vt, ushort_t* __restrict__ O) {
  const int wave = threadIdx.x >> 6;
  const int lane = threadIdx.x & 63;
  const int l15 = lane & 15, quad = lane >> 4;
  const int bh = blockIdx.y;
  const int b = bh >> 4, h = bh & 15;
  const int wl = blockIdx.x * 4 + wave;            // 0..63 per bh
  const int g  = (wl & 1) ? (63 - (wl >> 1)) : (wl >> 1);
  const int q0 = g * 32;

  __shared__ ushort_t Plds[4][2][16 * PPAD];

  const ushort_t* Kbh = Kb + (size_t)bh * S_ * DH_;
  const ushort_t* Vbh = Vt + (size_t)bh * DH_ * S_;

  bf16x8 qb[2][2];
  #pragma unroll
  for (int t = 0; t < 2; ++t) {
    const ushort_t* qptr = Qb + ((size_t)bh * S_ + q0 + t * 16 + l15) * DH_ + quad * 8;
    qb[t][0] = *(const bf16x8*)(qptr);
    qb[t][1] = *(const bf16x8*)(qptr + 32);
  }

  f32x4 o_acc[2][4] = {};
  float m_run[2] = {-1e30f, -1e30f}, l_run[2] = {0.0f, 0.0f};

  const int nch = (q0 >> 6) + 1;

  bf16x8 ka[4][2];
  #pragma unroll
  for (int kt = 0; kt < 4; ++kt) {
    const ushort_t* kp = Kbh + (size_t)(kt * 16 + l15) * DH_ + quad * 8;
    ka[kt][0] = *(const bf16x8*)kp;
    ka[kt][1] = *(const bf16x8*)(kp + 32);
  }

  for (int c = 0; c < nch; ++c) {
    const int k0 = c << 6;

    bf16x8 va[4][2];
    #pragma unroll
    for (int mt = 0; mt < 4; ++mt) {
      const ushort_t* vp = Vbh + (size_t)(mt * 16 + l15) * S_ + k0 + quad * 8;
      va[mt][0] = *(const bf16x8*)vp;
      va[mt][1] = *(const bf16x8*)(vp + 32);
    }

    f32x4 st[2][4];
    #pragma unroll
    for (int t = 0; t < 2; ++t)
      #pragma unroll
      for (int kt = 0; kt < 4; ++kt) {
        f32x4 z = {0.0f, 0.0f, 0.0f, 0.0f};
        z = __builtin_amdgcn_mfma_f32_16x16x32_bf16(ka[kt][0], qb[t][0], z, 0, 0, 0);
        z = __builtin_amdgcn_mfma_f32_16x16x32_bf16(ka[kt][1], qb[t][1], z, 0, 0, 0);
        st[t][kt] = z;
      }

    if (c + 1 < nch) {
      const int k1 = (c + 1) << 6;
      bf16x8 kan[4][2];
      #pragma unroll
      for (int kt = 0; kt < 4; ++kt) {
        const ushort_t* kp = Kbh + (size_t)(k1 + kt * 16 + l15) * DH_ + quad * 8;
        kan[kt][0] = *(const bf16x8*)kp;
        kan[kt][1] = *(const bf16x8*)(kp + 32);
      }
      #pragma unroll
      for (int kt = 0; kt < 4; ++kt) { ka[kt][0] = kan[kt][0]; ka[kt][1] = kan[kt][1]; }
    }

    if (c == nch - 1) {
      #pragma unroll
      for (int t = 0; t < 2; ++t) {
        const int query = q0 + t * 16 + l15;
        #pragma unroll
        for (int kt = 0; kt < 4; ++kt)
          #pragma unroll
          for (int r = 0; r < 4; ++r)
            if (k0 + kt * 16 + quad * 4 + r > query) st[t][kt][r] = -1e30f;
      }
    }

    #pragma unroll
    for (int t = 0; t < 2; ++t) {
      float mx = -1e30f;
      #pragma unroll
      for (int kt = 0; kt < 4; ++kt)
        #pragma unroll
        for (int r = 0; r < 4; ++r) mx = fmaxf(mx, st[t][kt][r]);
      mx = fmaxf(mx, __shfl_xor(mx, 16, 64));
      mx = fmaxf(mx, __shfl_xor(mx, 32, 64));
      const float m_new = fmaxf(m_run[t], mx);
      const float alpha = __expf(m_run[t] - m_new);
      float rs = 0.0f;
      #pragma unroll
      for (int kt = 0; kt < 4; ++kt)
        #pragma unroll
        for (int r = 0; r < 4; ++r) {
          const float e = __expf(st[t][kt][r] - m_new);
          st[t][kt][r] = e;
          rs += e;
        }
      rs += __shfl_xor(rs, 16, 64);
      rs += __shfl_xor(rs, 32, 64);
      l_run[t] = l_run[t] * alpha + rs;
      m_run[t] = m_new;
      #pragma unroll
      for (int mt = 0; mt < 4; ++mt)
        #pragma unroll
        for (int r = 0; r < 4; ++r) o_acc[t][mt][r] *= alpha;
    }

    #pragma unroll
    for (int t = 0; t < 2; ++t) {
      ushort_t* Pw = &Plds[wave][t][0];
      #pragma unroll
      for (int kt = 0; kt < 4; ++kt) {
        u32x2 wpair;
        wpair[0] = (unsigned)f2bf(st[t][kt][0]) | ((unsigned)f2bf(st[t][kt][1]) << 16);
        wpair[1] = (unsigned)f2bf(st[t][kt][2]) | ((unsigned)f2bf(st[t][kt][3]) << 16);
        *(u32x2*)&Pw[l15 * PPAD + kt * 16 + quad * 4] = wpair;
      }
      asm volatile("s_waitcnt lgkmcnt(0)" ::: "memory");
      const bf16x8 pb0 = *(const bf16x8*)&Pw[l15 * PPAD + quad * 8];
      const bf16x8 pb1 = *(const bf16x8*)&Pw[l15 * PPAD + 32 + quad * 8];
      #pragma unroll
      for (int mt = 0; mt < 4; ++mt) {
        o_acc[t][mt] = __builtin_amdgcn_mfma_f32_16x16x32_bf16(va[mt][0], pb0, o_acc[t][mt], 0, 0, 0);
        o_acc[t][mt] = __builtin_amdgcn_mfma_f32_16x16x32_bf16(va[mt][1], pb1, o_acc[t][mt], 0, 0, 0);
      }
    }
  }

  #pragma unroll
  for (int t = 0; t < 2; ++t) {
    const float inv = 1.0f / l_run[t];
    #pragma unroll
    for (int mt = 0; mt < 4; ++mt) {
      u16x4 pk;
      #pragma unroll
      for (int r = 0; r < 4; ++r) pk[r] = f2bf(o_acc[t][mt][r] * inv);
      *(u16x4*)&O[(((size_t)b * S_ + q0 + t * 16 + l15) * H_ + h) * DH_ + mt * 16 + quad * 4] = pk;
    }
  }
}

// ---------------------------------------------------------------------------
extern "C" void kernel_launch(void* const* d_in, const int* in_sizes, int n_in,
                              void* d_out, int out_size, void* d_ws, size_t ws_size,
                              hipStream_t stream) {
  const float* x       = (const float*)d_in[0];
  const float* rot_cos = (const float*)d_in[1];
  const float* rot_sin = (const float*)d_in[2];
  const float* ln1_w   = (const float*)d_in[3];
  const float* w_qkv   = (const float*)d_in[4];
  const float* w_out   = (const float*)d_in[5];
  const float* ln2_w   = (const float*)d_in[6];
  const float* w_mlp1  = (const float*)d_in[7];
  const float* b_mlp1  = (const float*)d_in[8];
  const float* w_mlp2  = (const float*)d_in[9];
  const float* b_mlp2  = (const float*)d_in[10];
  float* out = (float*)d_out;

  char* wsb = (char*)d_ws;
  const size_t MB = 1u << 20;
  ushort_t* h1_bf  = (ushort_t*)(wsb + 0 * MB);    // 8 MB  (reused as h2)
  ushort_t* qkv_bf = (ushort_t*)(wsb + 8 * MB);    // 24 MB (V third unused)
  ushort_t* q_bf   = (ushort_t*)(wsb + 32 * MB);   // 8 MB
  ushort_t* k_bf   = (ushort_t*)(wsb + 40 * MB);   // 8 MB
  ushort_t* v_t    = (ushort_t*)(wsb + 48 * MB);   // 8 MB (B,H,Dh,S)
  ushort_t* o_bf   = (ushort_t*)(wsb + 56 * MB);   // 8 MB
  float*    x2     = (float*)   (wsb + 64 * MB);   // 16 MB
  ushort_t* u_bf   = (ushort_t*)(wsb + 80 * MB);   // 32 MB
  ushort_t* wq_bf  = (ushort_t*)(wsb + 112 * MB);  // 6 MB
  ushort_t* wo_bf  = (ushort_t*)(wsb + 118 * MB);  // 2 MB
  ushort_t* w1_bf  = (ushort_t*)(wsb + 120 * MB);  // 8 MB
  ushort_t* w2_bf  = (ushort_t*)(wsb + 128 * MB);  // 8 MB -> 136 MB total
  (void)ws_size; (void)in_sizes; (void)n_in; (void)out_size;

  dim3 b256(256);

  // 0) weights -> bf16
  cast_w_kernel<<<dim3(4096, 4), b256, 0, stream>>>(
      w_qkv, wq_bf, 3 * D_ * D_, w_out, wo_bf, D_ * D_,
      w_mlp1, w1_bf, MLP_ * D_, w_mlp2, w2_bf, MLP_ * D_);
  // 1) h1 = LN(x) * ln1_w -> bf16
  ln_kernel<<<dim3(ROWS_), b256, 0, stream>>>(x, ln1_w, h1_bf);
  // 2) qkv = h1 @ w_qkv^T; q,k -> qkv_bf, V -> v_t (B,H,Dh,S)
  //    32x24 tiles, rects 2x4 -> sm=16, sn=6
  gemm_bt<0, 1, 1><<<dim3(768), b256, 0, stream>>>(
      h1_bf, wq_bf, nullptr, nullptr, qkv_bf, v_t, ROWS_, 3 * D_, D_, 16, 6, 4);
  // 3) rope q,k -> (B,H,S,Dh) bf16
  rope_kernel<<<dim3(ROWS_), b256, 0, stream>>>(qkv_bf, rot_cos, rot_sin, q_bf, k_bf);
  // 4) flash attention -> o (B,S,H,Dh) bf16
  attn_kernel<<<dim3(16, B_ * H_), b256, 0, stream>>>(q_bf, k_bf, v_t, o_bf);
  // 5) x2 = x + o @ w_out^T -> fp32   64x8 tiles of 64x128, rects 4x2 -> sm=16, sn=4
  gemm64_bt<4, 0><<<dim3(512), b256, 0, stream>>>(
      o_bf, wo_bf, nullptr, x, x2, ROWS_, D_, D_, 16, 4, 2);
  // 6) h2 = LN(x2) * ln2_w -> bf16
  ln_kernel<<<dim3(ROWS_), b256, 0, stream>>>(x2, ln2_w, h1_bf);
  // 7) u = gelu(h2 @ w_mlp1^T + b1) -> bf16  32x32 tiles, rects 2x4 -> sm=16, sn=8
  gemm_bt<3, 1, 0><<<dim3(1024), b256, 0, stream>>>(
      h1_bf, w1_bf, b_mlp1, nullptr, u_bf, nullptr, ROWS_, MLP_, D_, 16, 8, 4);
  // 8) out = x2 + u @ w_mlp2^T + b2 -> fp32  64x8 tiles of 64x128, rects 4x2
  gemm64_bt<5, 0><<<dim3(512), b256, 0, stream>>>(
      u_bf, w2_bf, b_mlp2, x2, out, ROWS_, D_, MLP_, 16, 4, 2);
}